// Round 8
// baseline (714.460 us; speedup 1.0000x reference)
//
#include <hip/hip_runtime.h>
#include <float.h>

// VQVAE forward, MI355X. Inputs f32, output buffer f32, order [encoded |
// decoded | vq_loss]; harness compares after bf16-rounding both sides.
// KEY (R7 forensics): the np reference computes the VQ distances in FLOAT32
// including the shared ||z||^2 (~0.9) term -> near-ties quantize equal in
// f32 (ULP ~6e-8) and np.argmin tie-breaks FIRST-INDEX. Exact-f64 argmin
// flips those ties (R7: ~1-3 pixels, absmax 421*2^-17). This version
// emulates the np f32 pipeline bit-for-bit: f32 FMA convs (im2col tap order
// ci,ky,kx; bias post-add), numpy pairwise-32 sums, sequential-FMA dot,
// dist=(a+b_k)-2*m_k in f32, first-index argmin, enc = z + (z_q - z) in f32.
#pragma clang fp contract(off)
// (explicit fmaf() still emits hardware FMA; everything else stays per-op IEEE)

// numpy pairwise_sum for n=32: r[j]=a[j]; r[j]+=a[8+j]; +=a[16+j]; +=a[24+j];
// result = ((r0+r1)+(r2+r3))+((r4+r5)+(r6+r7))
__device__ __forceinline__ float pw32(const float* p) {
  float r0 = p[0], r1 = p[1], r2 = p[2], r3 = p[3];
  float r4 = p[4], r5 = p[5], r6 = p[6], r7 = p[7];
  r0 += p[8];  r1 += p[9];  r2 += p[10]; r3 += p[11];
  r4 += p[12]; r5 += p[13]; r6 += p[14]; r7 += p[15];
  r0 += p[16]; r1 += p[17]; r2 += p[18]; r3 += p[19];
  r4 += p[20]; r5 += p[21]; r6 += p[22]; r7 += p[23];
  r0 += p[24]; r1 += p[25]; r2 += p[26]; r3 += p[27];
  r4 += p[28]; r5 += p[29]; r6 += p[30]; r7 += p[31];
  return ((r0 + r1) + (r2 + r3)) + ((r4 + r5) + (r6 + r7));
}

// ---- conv1: f32 FMA, taps (ci,r,c) ascending, bias post-add, relu ----
__global__ __launch_bounds__(256) void k_conv1(
    const float* __restrict__ img, const float* __restrict__ w1,
    const float* __restrict__ b1, float* __restrict__ h1, int b0) {
  __shared__ float w[768]; // (16,3,4,4)
  for (int i = threadIdx.x; i < 768; i += 256) w[i] = w1[i];
  __syncthreads();
  int idx = blockIdx.x * 256 + threadIdx.x;   // bl*2^18 + co*2^14 + y*2^7 + x
  int x  = idx & 127;
  int y  = (idx >> 7) & 127;
  int co = (idx >> 14) & 15;
  int bl = idx >> 18;
  const float* im = img + (long)(b0 + bl) * 196608;
  float a = 0.f;
  int iy0 = 2 * y - 1, ix0 = 2 * x - 1;
  for (int ci = 0; ci < 3; ci++) {
    const float* imc = im + ci * 65536;
    const float* wc  = w + co * 48 + ci * 16;
    for (int r = 0; r < 4; r++) {
      int iy = iy0 + r;
      if ((unsigned)iy >= 256u) continue;     // zero tap: fma(0,w,a)==a exact
      const float* row = imc + iy * 256;
      for (int c = 0; c < 4; c++) {
        int ix = ix0 + c;
        if ((unsigned)ix >= 256u) continue;
        a = fmaf(row[ix], wc[r * 4 + c], a);
      }
    }
  }
  a = a + b1[co];                              // bias added after conv (f32)
  h1[idx] = fmaxf(a, 0.f);
}

// ---- conv2 (f32 FMA) + relu + np-f32 VQ argmin + enc write + loss ----
__global__ __launch_bounds__(256) void k_conv2vq(
    const float* __restrict__ h1, const float* __restrict__ w2,
    const float* __restrict__ b2, const float* __restrict__ cb,
    float* __restrict__ enc, double* __restrict__ loss, int b0) {
  __shared__ float w[8192];    // w2 (32,16,4,4): co*256 + ci*16 + r*4 + c
  __shared__ float cbs[16384]; // (512,32)
  __shared__ float bn[512];    // ||c_k||^2, np pairwise-32, f32
  __shared__ double red[256];
  int t = threadIdx.x;
  for (int i = t; i < 8192; i += 256) w[i] = w2[i];
  for (int i = t; i < 16384; i += 256) cbs[i] = cb[i];
  __syncthreads();
  for (int k = t; k < 512; k += 256) {
    float p[32];
    #pragma unroll
    for (int d = 0; d < 32; d++) { float c = cbs[k * 32 + d]; p[d] = c * c; }
    bn[k] = pw32(p);
  }
  __syncthreads();

  int ppix = blockIdx.x * 256 + t;  // bl*4096 + y*64 + x
  int x  = ppix & 63;
  int y  = (ppix >> 6) & 63;
  int bl = ppix >> 12;
  int bg = b0 + bl;

  float z[32];
  #pragma unroll
  for (int q = 0; q < 32; q++) z[q] = 0.f;

  // taps (ci,r,c) ascending, f32 FMA per output channel
  int iy0 = 2 * y - 1, ix0 = 2 * x - 1;
  for (int ci = 0; ci < 16; ci++) {
    long hbase = (long)bl * 262144 + (long)ci * 16384;
    for (int r = 0; r < 4; r++) {
      int iy = iy0 + r;
      if ((unsigned)iy >= 128u) continue;     // wave-uniform
      const float* hrow = h1 + hbase + (long)iy * 128;
      for (int c = 0; c < 4; c++) {
        int ix = ix0 + c;
        float hv = ((unsigned)ix < 128u) ? hrow[ix] : 0.f;
        const float* wp = w + ci * 16 + r * 4 + c;   // + co*256
        #pragma unroll
        for (int co = 0; co < 32; co++)
          z[co] = fmaf(hv, wp[co * 256], z[co]);
      }
    }
  }
  #pragma unroll
  for (int q = 0; q < 32; q++) {
    z[q] = z[q] + b2[q];                      // bias post-add
    z[q] = fmaxf(z[q], 0.f);                  // relu
  }

  // a = ||z||^2 via np pairwise-32 of f32 products
  float pz[32];
  #pragma unroll
  for (int d = 0; d < 32; d++) pz[d] = z[d] * z[d];
  float a = pw32(pz);

  // dist_k = (a + b_k) - 2*m_k, all f32; m_k = sequential FMA dot (BLAS-like)
  float best = FLT_MAX; int bq = 0;
  for (int k = 0; k < 512; k++) {
    const float* ck = cbs + (k << 5);
    float m = 0.f;
    #pragma unroll
    for (int d = 0; d < 32; d++) m = fmaf(z[d], ck[d], m);
    float dist = (a + bn[k]) - 2.0f * m;
    if (dist < best) { best = dist; bq = k; }  // strict < == np first-index
  }

  double ls = 0.0;
  const float* cw = cbs + (bq << 5);
  #pragma unroll
  for (int d = 0; d < 32; d++) {
    float df = cw[d] - z[d];                  // f32, as ref computes z_q - z
    float ev = z[d] + df;                     // straight-through forward value
    enc[(long)bg * 131072 + (long)d * 4096 + y * 64 + x] = ev;
    ls += (double)df * (double)df;
  }
  red[t] = ls;
  __syncthreads();
  for (int s = 128; s > 0; s >>= 1) {
    if (t < s) red[t] += red[t + s];
    __syncthreads();
  }
  if (t == 0) atomicAdd(loss, red[0]);
}

// ---- deconv1: ConvT(32->16,k4,s2,p1)+relu, f32 ----
__global__ __launch_bounds__(256) void k_deconv1(
    const float* __restrict__ enc, const float* __restrict__ dw1,
    const float* __restrict__ db1, float* __restrict__ d1, int b0) {
  __shared__ float w[8192];   // dw1 (32,16,4,4): ci*256 + co*16 + ky*4 + kx
  for (int i = threadIdx.x; i < 8192; i += 256) w[i] = dw1[i];
  __syncthreads();
  int idx = blockIdx.x * 256 + threadIdx.x;   // bl*2^18 + co*2^14 + oy*2^7 + ox
  int ox = idx & 127;
  int oy = (idx >> 7) & 127;
  int co = (idx >> 14) & 15;
  int bl = idx >> 18;
  long ebase = (long)(b0 + bl) * 131072;
  float acc = 0.f;
  int iyt = (oy + 1) >> 1, ixt = (ox + 1) >> 1;
  for (int sy = 0; sy < 2; sy++) {
    int iy = iyt - sy;
    int ky = oy + 1 - 2 * iy;
    if ((unsigned)iy >= 64u || (unsigned)ky >= 4u) continue;
    for (int sx = 0; sx < 2; sx++) {
      int ix = ixt - sx;
      int kx = ox + 1 - 2 * ix;
      if ((unsigned)ix >= 64u || (unsigned)kx >= 4u) continue;
      const float* ep = enc + ebase + iy * 64 + ix;   // + ci*4096
      const float* wp = w + co * 16 + ky * 4 + kx;    // + ci*256
      #pragma unroll
      for (int ci = 0; ci < 32; ci++)
        acc = fmaf(ep[ci * 4096], wp[ci * 256], acc);
    }
  }
  acc = acc + db1[co];
  d1[idx] = fmaxf(acc, 0.f);
}

// ---- deconv2: ConvT(16->3,k4,s2,p1)+relu -> dec f32 ----
__global__ __launch_bounds__(256) void k_deconv2(
    const float* __restrict__ d1, const float* __restrict__ dw2,
    const float* __restrict__ db2, float* __restrict__ dec, int b0) {
  __shared__ float w[768];    // dw2 (16,3,4,4): ci*48 + co*16 + ky*4 + kx
  for (int i = threadIdx.x; i < 768; i += 256) w[i] = dw2[i];
  __syncthreads();
  int idx = blockIdx.x * 256 + threadIdx.x;  // (bl*3+co)*65536 + oy*256 + ox
  int ox = idx & 255;
  int oy = (idx >> 8) & 255;
  int bc = idx >> 16;
  int co = bc % 3;
  int bl = bc / 3;
  int bg = b0 + bl;
  long dbase = (long)bl * 262144;
  float acc = 0.f;
  int iyt = (oy + 1) >> 1, ixt = (ox + 1) >> 1;
  for (int sy = 0; sy < 2; sy++) {
    int iy = iyt - sy;
    int ky = oy + 1 - 2 * iy;
    if ((unsigned)iy >= 128u || (unsigned)ky >= 4u) continue;
    for (int sx = 0; sx < 2; sx++) {
      int ix = ixt - sx;
      int kx = ox + 1 - 2 * ix;
      if ((unsigned)ix >= 128u || (unsigned)kx >= 4u) continue;
      const float* dp = d1 + dbase + (long)iy * 128 + ix;  // + ci*16384
      const float* wp = w + co * 16 + ky * 4 + kx;         // + ci*48
      #pragma unroll
      for (int ci = 0; ci < 16; ci++)
        acc = fmaf(dp[ci * 16384], wp[ci * 48], acc);
    }
  }
  acc = acc + db2[co];
  dec[(long)(bg * 3 + co) * 65536 + oy * 256 + ox] = fmaxf(acc, 0.f);
}

__global__ void k_loss(const double* __restrict__ loss, float* __restrict__ out) {
  if (threadIdx.x == 0) out[0] = (float)(2.0 * loss[0] / 4194304.0);
}

extern "C" void kernel_launch(void* const* d_in, const int* in_sizes, int n_in,
                              void* d_out, int out_size, void* d_ws, size_t ws_size,
                              hipStream_t stream) {
  const float* imgs = (const float*)d_in[0];
  const float* w1   = (const float*)d_in[1];
  const float* b1   = (const float*)d_in[2];
  const float* w2   = (const float*)d_in[3];
  const float* b2   = (const float*)d_in[4];
  const float* cb   = (const float*)d_in[5];
  const float* dw1  = (const float*)d_in[6];
  const float* db1  = (const float*)d_in[7];
  const float* dw2  = (const float*)d_in[8];
  const float* db2  = (const float*)d_in[9];

  float* out = (float*)d_out;
  float* enc = out;               // (32,32,64,64)  f32
  float* dec = out + 4194304;     // (32,3,256,256) f32
  float* vql = out + 10485760;    // scalar         f32

  long ws = (long)ws_size;
  double* loss = (double*)((char*)d_ws + ((ws - 8) & ~7L));
  hipMemsetAsync(loss, 0, sizeof(double), stream);

  // h1 / d1: f32, 1 MiB per image; batch-chunked through ws
  int cc = 1;
  for (int c = 32; c >= 1; c >>= 1)
    if ((long)c * 1048576 + 16 <= ws) { cc = c; break; }

  float* h1 = (float*)d_ws;
  for (int b0 = 0; b0 < 32; b0 += cc) {
    k_conv1<<<cc * 1024, 256, 0, stream>>>(imgs, w1, b1, h1, b0);
    k_conv2vq<<<cc * 16, 256, 0, stream>>>(h1, w2, b2, cb, enc, loss, b0);
  }

  float* d1 = (float*)d_ws;
  for (int b0 = 0; b0 < 32; b0 += cc) {
    k_deconv1<<<cc * 1024, 256, 0, stream>>>(enc, dw1, db1, d1, b0);
    k_deconv2<<<cc * 768, 256, 0, stream>>>(d1, dw2, db2, dec, b0);
  }

  k_loss<<<1, 64, 0, stream>>>(loss, vql);
}